// Round 10
// baseline (49.765 us; speedup 1.0000x reference)
//
#include <hip/hip_runtime.h>

#define BSES 64
#define EDIM 128
#define HDIM 128
#define KSCALE 2.8853900817779268f  // 2*log2(e): exp(2x) = exp2(KSCALE*x)

__device__ __forceinline__ float fexp2(float x) {
#if __has_builtin(__builtin_amdgcn_exp2f)
  return __builtin_amdgcn_exp2f(x);
#else
  return exp2f(x);
#endif
}
__device__ __forceinline__ float frcp(float x) {
#if __has_builtin(__builtin_amdgcn_rcpf)
  return __builtin_amdgcn_rcpf(x);
#else
  return 1.0f / x;
#endif
}

// 4-way batched reciprocal sum: w0/x0 + w1/x1 + w2/x2 + w3/x3,
// x_j = fma(s_j, v_j, 1). 13 VALU + 1 rcp per 4 elements. (Proven R3+.)
__device__ __forceinline__ float g4(float s0, float s1, float s2, float s3,
                                    float w0, float w1, float w2, float w3,
                                    float4 v, float acc) {
  float x0 = fmaf(s0, v.x, 1.f);
  float x1 = fmaf(s1, v.y, 1.f);
  float x2 = fmaf(s2, v.z, 1.f);
  float x3 = fmaf(s3, v.w, 1.f);
  float p01 = x0 * x1, p23 = x2 * x3;
  float n01 = fmaf(w1, x0, w0 * x1);
  float n23 = fmaf(w3, x2, w2 * x3);
  float num = fmaf(n23, p01, n01 * p23);
  return fmaf(num, frcp(p01 * p23), acc);
}

// Fused projections (R3-proven shape). Blocks [0,nbTP): etp[n][h] natural
// layout. Blocks [nbTP,..): esp4 PACKED [h/4][b][4] (one coalesced dwordx4
// per lane per h-quad in k2); plus C = sum(W3)+b3.
__global__ __launch_bounds__(256) void taa_k1(
    const float* __restrict__ sess, const float* __restrict__ W1,
    const float* __restrict__ b1, const float* __restrict__ emb,
    const float* __restrict__ W2, const float* __restrict__ b2,
    const float* __restrict__ W3, const float* __restrict__ b3,
    float* __restrict__ etp, float* __restrict__ esp4,
    float* __restrict__ C_out, int N, int nbTP) {
  if ((int)blockIdx.x < nbTP) {
    __shared__ float sm[32][132];  // emb tile, padded stride
    const int nb = blockIdx.x * 32;
    for (int k = threadIdx.x; k < 32 * 32; k += 256) {
      int r = k >> 5, c4 = k & 31;
      float4 v = make_float4(0.f, 0.f, 0.f, 0.f);
      if (nb + r < N) v = ((const float4*)(emb + (size_t)(nb + r) * EDIM))[c4];
      *(float4*)&sm[r][c4 * 4] = v;
    }
    __syncthreads();
    const int h4 = (threadIdx.x & 31) * 4;
    const int rg = threadIdx.x >> 5;  // 8 groups of 4 rows
    float acc[4][4];
#pragma unroll
    for (int j = 0; j < 4; ++j)
#pragma unroll
      for (int q = 0; q < 4; ++q) acc[j][q] = 0.f;
    for (int e = 0; e < EDIM; e += 4) {
      float4 w[4];
#pragma unroll
      for (int q = 0; q < 4; ++q)
        w[q] = *(const float4*)(W2 + (size_t)(e + q) * HDIM + h4);
#pragma unroll
      for (int j = 0; j < 4; ++j) {
        float4 em = *(const float4*)&sm[rg * 4 + j][e];
        acc[j][0] = fmaf(em.x, w[0].x, acc[j][0]);
        acc[j][1] = fmaf(em.x, w[0].y, acc[j][1]);
        acc[j][2] = fmaf(em.x, w[0].z, acc[j][2]);
        acc[j][3] = fmaf(em.x, w[0].w, acc[j][3]);
        acc[j][0] = fmaf(em.y, w[1].x, acc[j][0]);
        acc[j][1] = fmaf(em.y, w[1].y, acc[j][1]);
        acc[j][2] = fmaf(em.y, w[1].z, acc[j][2]);
        acc[j][3] = fmaf(em.y, w[1].w, acc[j][3]);
        acc[j][0] = fmaf(em.z, w[2].x, acc[j][0]);
        acc[j][1] = fmaf(em.z, w[2].y, acc[j][1]);
        acc[j][2] = fmaf(em.z, w[2].z, acc[j][2]);
        acc[j][3] = fmaf(em.z, w[2].w, acc[j][3]);
        acc[j][0] = fmaf(em.w, w[3].x, acc[j][0]);
        acc[j][1] = fmaf(em.w, w[3].y, acc[j][1]);
        acc[j][2] = fmaf(em.w, w[3].z, acc[j][2]);
        acc[j][3] = fmaf(em.w, w[3].w, acc[j][3]);
      }
    }
    float4 bb2 = *(const float4*)(b2 + h4);
#pragma unroll
    for (int j = 0; j < 4; ++j) {
      int n = nb + rg * 4 + j;
      if (n < N) {
        float4 o;
        o.x = fexp2((acc[j][0] + bb2.x) * KSCALE);
        o.y = fexp2((acc[j][1] + bb2.y) * KSCALE);
        o.z = fexp2((acc[j][2] + bb2.z) * KSCALE);
        o.w = fexp2((acc[j][3] + bb2.w) * KSCALE);
        *(float4*)(etp + (size_t)n * HDIM + h4) = o;
      }
    }
  } else {
    int t = ((int)blockIdx.x - nbTP) * 256 + threadIdx.x;
    if (t < BSES * HDIM) {
      int b = t >> 7, h = t & 127;
      const float* srow = sess + b * EDIM;
      float acc = 0.f;
#pragma unroll 4
      for (int e = 0; e < EDIM; ++e)
        acc = fmaf(srow[e], W1[e * HDIM + h], acc);
      esp4[(h >> 2) * 256 + b * 4 + (h & 3)] = fexp2((acc + b1[h]) * KSCALE);
    }
    if (t == 0) {
      float s = b3[0];
      for (int i = 0; i < HDIM; ++i) s += W3[i];
      *C_out = s;
    }
  }
}

// One 16-h chunk at offset cc using session regs S[4] (float4 = 4 h-quads).
// tv loads are wave-uniform broadcasts; w3 uniform -> s_load.
#define CHUNK(S, cc)                                                        \
  {                                                                         \
    float wv_[16];                                                          \
    _Pragma("unroll") for (int k = 0; k < 16; ++k) wv_[k] = w3[(cc) + k];   \
    _Pragma("unroll") for (int i = 0; i < 4; ++i) {                         \
      const float4* t4 = (const float4*)(tr + i * HDIM + (cc));             \
      float4 v0 = t4[0], v1 = t4[1], v2 = t4[2], v3 = t4[3];                \
      acc[i] = g4(S[0].x, S[0].y, S[0].z, S[0].w, wv_[0], wv_[1], wv_[2],   \
                  wv_[3], v0, acc[i]);                                      \
      acc[i] = g4(S[1].x, S[1].y, S[1].z, S[1].w, wv_[4], wv_[5], wv_[6],   \
                  wv_[7], v1, acc[i]);                                      \
      acc[i] = g4(S[2].x, S[2].y, S[2].z, S[2].w, wv_[8], wv_[9], wv_[10],  \
                  wv_[11], v2, acc[i]);                                     \
      acc[i] = g4(S[3].x, S[3].y, S[3].z, S[3].w, wv_[12], wv_[13],         \
                  wv_[14], wv_[15], v3, acc[i]);                            \
    }                                                                       \
  }

// Scoring (R3's proven structure + g4 + named-buffer 2-chunk pipeline).
// lane = session b; wave -> 4 targets. sA/sB: next chunk's esp4 loads issue
// under current chunk's g4 math (all static indexing; no full unroll).
// score[b][n] = C - 2 * sum_h w3[h] * rcp(fma(esp[b][h], etp[n][h], 1))
__global__ __launch_bounds__(256) void taa_k2(
    const float* __restrict__ etp, const float* __restrict__ esp4,
    const float* __restrict__ w3, const float* __restrict__ Cptr,
    float* __restrict__ out, int N) {
  const int lane = threadIdx.x & 63;
  const int wave = blockIdx.x * (blockDim.x >> 6) + (threadIdx.x >> 6);
  const int n0 = wave * 4;
  if (n0 >= N) return;
  const float* tr = etp + (size_t)n0 * HDIM;
  float acc[4] = {0.f, 0.f, 0.f, 0.f};
  float4 sA[4], sB[4];
#pragma unroll
  for (int k = 0; k < 4; ++k)
    sA[k] = *(const float4*)(esp4 + (k << 8) + (lane << 2));  // chunk 0
#pragma unroll 1
  for (int c = 0; c < HDIM; c += 32) {
    const int q0 = c >> 2;
#pragma unroll
    for (int k = 0; k < 4; ++k)  // prefetch chunk c+16
      sB[k] = *(const float4*)(esp4 + ((q0 + 4 + k) << 8) + (lane << 2));
    CHUNK(sA, c)
    if (c + 32 < HDIM) {
#pragma unroll
      for (int k = 0; k < 4; ++k)  // prefetch chunk c+32
        sA[k] = *(const float4*)(esp4 + ((q0 + 8 + k) << 8) + (lane << 2));
    }
    CHUNK(sB, c + 16)
  }
  const float Cv = *Cptr;  // uniform -> s_load
  float4 res;
  res.x = fmaf(-2.f, acc[0], Cv);
  res.y = fmaf(-2.f, acc[1], Cv);
  res.z = fmaf(-2.f, acc[2], Cv);
  res.w = fmaf(-2.f, acc[3], Cv);
  if (n0 + 3 < N) {
    *(float4*)(out + (size_t)lane * N + n0) = res;
  } else {
    float r4[4] = {res.x, res.y, res.z, res.w};
    for (int i = 0; i < 4 && n0 + i < N; ++i) out[(size_t)lane * N + n0 + i] = r4[i];
  }
}

extern "C" void kernel_launch(void* const* d_in, const int* in_sizes, int n_in,
                              void* d_out, int out_size, void* d_ws, size_t ws_size,
                              hipStream_t stream) {
  const float* sess = (const float*)d_in[0];
  const float* emb  = (const float*)d_in[1];
  const float* W1   = (const float*)d_in[2];
  const float* b1   = (const float*)d_in[3];
  const float* W2   = (const float*)d_in[4];
  const float* b2   = (const float*)d_in[5];
  const float* W3   = (const float*)d_in[6];
  const float* b3   = (const float*)d_in[7];
  float* out = (float*)d_out;
  const int B = in_sizes[0] / EDIM;   // 64
  const int N = in_sizes[1] / EDIM;   // 20000

  float* etp  = (float*)d_ws;                     // N*128 floats
  float* esp4 = etp + (size_t)N * HDIM;           // B*128 floats (packed)
  float* Cp   = esp4 + (size_t)BSES * HDIM;       // 1 float

  const int nbTP = (N + 31) / 32;                 // 625
  const int nbSP = (B * HDIM + 255) / 256;        // 32
  taa_k1<<<nbTP + nbSP, 256, 0, stream>>>(sess, W1, b1, emb, W2, b2, W3, b3,
                                          etp, esp4, Cp, N, nbTP);
  const int waves = (N + 3) / 4;
  taa_k2<<<(waves * 64 + 255) / 256, 256, 0, stream>>>(etp, esp4, W3, Cp, out, N);
}